// Round 7
// baseline (163.261 us; speedup 1.0000x reference)
//
#include <hip/hip_runtime.h>
#include <hip/hip_bf16.h>
#include <math.h>

#define TOKENS 8192
#define D_REAL 768
#define D_HID  512
#define D_MODEL 4096

typedef __attribute__((ext_vector_type(8))) short bf16x8;   // 8 bf16 in 4 VGPRs
typedef __attribute__((ext_vector_type(4))) float f32x4;    // MFMA accumulator

// fp32 -> bf16, round-to-nearest-even
__device__ inline unsigned short f2bf(float f) {
    union { float f; unsigned u; } v; v.f = f;
    unsigned r = v.u + 0x7FFFu + ((v.u >> 16) & 1u);
    return (unsigned short)(r >> 16);
}
__device__ inline float bf2f(unsigned short h) {
    union { unsigned u; float f; } v; v.u = ((unsigned)h) << 16;
    return v.f;
}

// async global->LDS, 16B per lane. LDS dest = wave-uniform base + lane*16.
__device__ inline void gload_lds16(const void* g, void* lds_wave_base) {
    __builtin_amdgcn_global_load_lds(
        (const __attribute__((address_space(1))) unsigned*)g,
        (__attribute__((address_space(3))) unsigned*)lds_wave_base,
        16, 0, 0);
}

// ---------------------------------------------------------------------------
// GEMM1: Hb[M=8192][N=512] = Ag[M][K=768] * w1b[N][K]^T, bf16 out.
// Tile 64x128, BK=32, 256 threads = 4 waves (2 row x 2 col), each wave
// 32x64 = 2x4 frags. 2-phase LDS double-buffer: stage(t+1) issued before
// compute(t); one barrier per K-step.
// ---------------------------------------------------------------------------
__global__ __launch_bounds__(256)
void gemm1_mfma(const unsigned short* __restrict__ A,
                const unsigned short* __restrict__ B,
                unsigned short* __restrict__ C)
{
    constexpr int K = D_REAL, N = D_HID, NT = K / 32;   // 24
    __shared__ __align__(16) unsigned short As[2][64 * 32];    // 2x4 KB
    __shared__ __align__(16) unsigned short Bs[2][128 * 32];   // 2x8 KB

    const int tid = threadIdx.x;
    const int rowBase = blockIdx.x * 64;
    const int colBase = blockIdx.y * 128;

    const int srow = tid >> 2;
    const int scol = (tid & 3) * 8;
    const unsigned short* gA = A + (size_t)(rowBase + srow) * K + scol;
    const unsigned short* gB = B + (size_t)(colBase + srow) * K + scol;
    const int wvoff = (tid >> 6) * 512;   // wave-uniform stage base (shorts)

    const int lane = tid & 63;
    const int wv   = tid >> 6;
    const int wm   = (wv >> 1) * 32;
    const int wn   = (wv & 1) * 64;
    const int frow = lane & 15;
    const int fk   = (lane >> 4) * 8;

    f32x4 acc[2][4];
    #pragma unroll
    for (int i = 0; i < 2; i++)
        #pragma unroll
        for (int j = 0; j < 4; j++) acc[i][j] = (f32x4)0.f;

    auto STAGE = [&](int buf, int t) {
        const unsigned short* pA = gA + t * 32;
        const unsigned short* pB = gB + t * 32;
        gload_lds16(pA,                &As[buf][wvoff]);
        gload_lds16(pB,                &Bs[buf][wvoff]);
        gload_lds16(pB + (size_t)64*K, &Bs[buf][wvoff + 2048]);
    };
    auto COMPUTE = [&](int buf) {
        bf16x8 af[2], bg[4];
        #pragma unroll
        for (int i = 0; i < 2; i++)
            af[i] = *reinterpret_cast<const bf16x8*>(&As[buf][(wm + i*16 + frow) * 32 + fk]);
        #pragma unroll
        for (int j = 0; j < 4; j++)
            bg[j] = *reinterpret_cast<const bf16x8*>(&Bs[buf][(wn + j*16 + frow) * 32 + fk]);
        #pragma unroll
        for (int i = 0; i < 2; i++)
            #pragma unroll
            for (int j = 0; j < 4; j++)
                acc[i][j] = __builtin_amdgcn_mfma_f32_16x16x32_bf16(af[i], bg[j], acc[i][j], 0, 0, 0);
    };

    STAGE(0, 0);
    __syncthreads();                 // vmcnt(0)+barrier: tile 0 ready
    #pragma unroll
    for (int t = 0; t < NT - 1; ++t) {
        const int cur = t & 1;
        STAGE(cur ^ 1, t + 1);       // issue next tile BEFORE compute
        COMPUTE(cur);
        __syncthreads();             // drains stage(t+1); all reads of cur done
    }
    COMPUTE((NT - 1) & 1);

    // Epilogue: bf16 scalar stores (C/D frag: row=(lane>>4)*4+r, col=lane&15)
    const int orow0 = wm + (lane >> 4) * 4;
    const int ocol0 = wn + frow;
    #pragma unroll
    for (int i = 0; i < 2; i++)
        #pragma unroll
        for (int r = 0; r < 4; r++) {
            unsigned short* dst = C + (size_t)(rowBase + orow0 + i*16 + r) * N + colBase + ocol0;
            #pragma unroll
            for (int j = 0; j < 4; j++)
                dst[j * 16] = f2bf(acc[i][j][r]);
        }
}

// ---------------------------------------------------------------------------
// GEMM2: out[M=8192][N=4096] = Hb * w2b^T + embed[ids], fp32 out.
// m97 tile (128x128, BK=32, 4 waves 2x2, 4x4 frags) + 2-phase double-buffer
// + XCD-slab swizzle (round 6) + scalar epilogue (round 2).
// ---------------------------------------------------------------------------
__global__ __launch_bounds__(256)
void gemm2_mfma(const unsigned short* __restrict__ A,
                const unsigned short* __restrict__ B,
                const int* __restrict__ ids,
                const float* __restrict__ embed,
                float* __restrict__ C)
{
    constexpr int K = D_HID, N = D_MODEL, NT = K / 32;   // 16
    __shared__ __align__(16) unsigned short As[2][128 * 32];   // 2x8 KB
    __shared__ __align__(16) unsigned short Bs[2][128 * 32];   // 2x8 KB
    __shared__ int sIds[128];

    // bijective slab swizzle: f&7 = XCD; XCD k owns row tiles k*8..k*8+7
    const int f   = blockIdx.x;          // 0..2047
    const int xcd = f & 7;
    const int idx = f >> 3;              // 0..255
    const int rowBase = (xcd * 8 + (idx & 7)) * 128;   // row tile 0..63
    const int colBase = (idx >> 3) * 128;              // col tile 0..31

    const int tid = threadIdx.x;
    if (tid < 128) sIds[tid] = ids[rowBase + tid];

    const int srow = tid >> 2;
    const int scol = (tid & 3) * 8;
    const unsigned short* gA = A + (size_t)(rowBase + srow) * K + scol;
    const unsigned short* gB = B + (size_t)(colBase + srow) * K + scol;
    const int wvoff = (tid >> 6) * 512;

    const int lane = tid & 63;
    const int wv   = tid >> 6;
    const int wm   = (wv >> 1) * 64;
    const int wn   = (wv & 1) * 64;
    const int frow = lane & 15;
    const int fk   = (lane >> 4) * 8;

    f32x4 acc[4][4];
    #pragma unroll
    for (int i = 0; i < 4; i++)
        #pragma unroll
        for (int j = 0; j < 4; j++) acc[i][j] = (f32x4)0.f;

    auto STAGE = [&](int buf, int t) {
        const unsigned short* pA = gA + t * 32;
        const unsigned short* pB = gB + t * 32;
        gload_lds16(pA,                &As[buf][wvoff]);
        gload_lds16(pA + (size_t)64*K, &As[buf][wvoff + 2048]);
        gload_lds16(pB,                &Bs[buf][wvoff]);
        gload_lds16(pB + (size_t)64*K, &Bs[buf][wvoff + 2048]);
    };
    auto COMPUTE = [&](int buf) {
        bf16x8 af[4], bg[4];
        #pragma unroll
        for (int i = 0; i < 4; i++)
            af[i] = *reinterpret_cast<const bf16x8*>(&As[buf][(wm + i*16 + frow) * 32 + fk]);
        #pragma unroll
        for (int j = 0; j < 4; j++)
            bg[j] = *reinterpret_cast<const bf16x8*>(&Bs[buf][(wn + j*16 + frow) * 32 + fk]);
        #pragma unroll
        for (int i = 0; i < 4; i++)
            #pragma unroll
            for (int j = 0; j < 4; j++)
                acc[i][j] = __builtin_amdgcn_mfma_f32_16x16x32_bf16(af[i], bg[j], acc[i][j], 0, 0, 0);
    };

    STAGE(0, 0);
    __syncthreads();
    #pragma unroll
    for (int t = 0; t < NT - 1; ++t) {
        const int cur = t & 1;
        STAGE(cur ^ 1, t + 1);
        COMPUTE(cur);
        __syncthreads();
    }
    COMPUTE((NT - 1) & 1);

    // Scalar epilogue: C/D frag row=(lane>>4)*4+r, col=lane&15.
    const int orow0 = wm + (lane >> 4) * 4;
    const int ocol0 = wn + frow;
    #pragma unroll
    for (int i = 0; i < 4; i++) {
        #pragma unroll
        for (int r = 0; r < 4; r++) {
            const int lrow = orow0 + i * 16 + r;
            const size_t grow = (size_t)(rowBase + lrow);
            const float* e = embed + (size_t)sIds[lrow] * N + colBase + ocol0;
            #pragma unroll
            for (int j = 0; j < 4; j++)
                C[grow * N + colBase + ocol0 + j * 16] = acc[i][j][r] + e[j * 16];
        }
    }
}

// ---------------------------------------------------------------------------
// fp32 -> bf16 bulk convert of w1 and w2 in one launch
// ---------------------------------------------------------------------------
__global__ __launch_bounds__(256)
void convert2_bf16(const float* __restrict__ s1, unsigned short* __restrict__ d1, int n1,
                   const float* __restrict__ s2, unsigned short* __restrict__ d2, int n2)
{
    int i = blockIdx.x * 256 + threadIdx.x;
    const float* src; unsigned short* dst;
    if (i < n1) { src = s1; dst = d1; }
    else {
        i -= n1;
        if (i >= n2) return;
        src = s2; dst = d2;
    }
    const float4 v = reinterpret_cast<const float4*>(src)[i];
    ushort4 o;
    o.x = f2bf(v.x); o.y = f2bf(v.y); o.z = f2bf(v.z); o.w = f2bf(v.w);
    reinterpret_cast<ushort4*>(dst)[i] = o;
}

// ---------------------------------------------------------------------------
// Gather rows of real[ids[t]] -> bf16 Ag[t]. One block (192 thr) per token.
// ---------------------------------------------------------------------------
__global__ __launch_bounds__(192)
void gather_bf16(const float* __restrict__ real, const int* __restrict__ ids,
                 unsigned short* __restrict__ Ag)
{
    const int row = blockIdx.x;
    const int t = threadIdx.x;
    const float4 v = *reinterpret_cast<const float4*>(real + (size_t)ids[row] * D_REAL + t * 4);
    ushort4 o;
    o.x = f2bf(v.x); o.y = f2bf(v.y); o.z = f2bf(v.z); o.w = f2bf(v.w);
    *reinterpret_cast<ushort4*>(Ag + (size_t)row * D_REAL + t * 4) = o;
}

// ---------------------------------------------------------------------------
// In-place LayerNorm + ELU on bf16 H [TOKENS][512]. One wave per row.
// ---------------------------------------------------------------------------
__global__ __launch_bounds__(256)
void ln_elu_bf16(unsigned short* __restrict__ H,
                 const float* __restrict__ ln_w, const float* __restrict__ ln_b)
{
    const int row = blockIdx.x * 4 + (threadIdx.x >> 6);
    const int t = threadIdx.x & 63;
    unsigned short* x = H + (size_t)row * D_HID + t * 8;

    bf16x8 v = *reinterpret_cast<const bf16x8*>(x);
    float f[8], s = 0.f, ss = 0.f;
    #pragma unroll
    for (int j = 0; j < 8; j++) {
        f[j] = bf2f((unsigned short)v[j]);
        s += f[j]; ss += f[j] * f[j];
    }
    #pragma unroll
    for (int off = 32; off > 0; off >>= 1) {
        s  += __shfl_down(s, off);
        ss += __shfl_down(ss, off);
    }
    s = __shfl(s, 0); ss = __shfl(ss, 0);
    const float mu = s * (1.f / D_HID);
    const float var = ss * (1.f / D_HID) - mu * mu;
    const float rstd = rsqrtf(var + 1e-5f);

    const float4 w0 = *reinterpret_cast<const float4*>(ln_w + t * 8);
    const float4 w1 = *reinterpret_cast<const float4*>(ln_w + t * 8 + 4);
    const float4 b0 = *reinterpret_cast<const float4*>(ln_b + t * 8);
    const float4 b1 = *reinterpret_cast<const float4*>(ln_b + t * 8 + 4);
    const float wa[8] = { w0.x, w0.y, w0.z, w0.w, w1.x, w1.y, w1.z, w1.w };
    const float ba[8] = { b0.x, b0.y, b0.z, b0.w, b1.x, b1.y, b1.z, b1.w };

    bf16x8 o;
    #pragma unroll
    for (int j = 0; j < 8; j++) {
        float y = (f[j] - mu) * rstd * wa[j] + ba[j];
        y = y > 0.f ? y : expm1f(y);
        o[j] = (short)f2bf(y);
    }
    *reinterpret_cast<bf16x8*>(x) = o;
}

extern "C" void kernel_launch(void* const* d_in, const int* in_sizes, int n_in,
                              void* d_out, int out_size, void* d_ws, size_t ws_size,
                              hipStream_t stream)
{
    const float* real  = (const float*)d_in[0];   // [32000, 768]
    const float* embed = (const float*)d_in[1];   // [32000, 4096]
    const float* w1    = (const float*)d_in[2];   // [512, 768]
    const float* w2    = (const float*)d_in[3];   // [4096, 512]
    const float* ln_w  = (const float*)d_in[4];   // [512]
    const float* ln_b  = (const float*)d_in[5];   // [512]
    const int*   ids   = (const int*)d_in[6];     // [8192]
    float* out = (float*)d_out;                   // [8192, 4096] fp32

    unsigned short* Hb  = (unsigned short*)d_ws;             // [8192][512] bf16 (8 MB)
    unsigned short* w1b = Hb  + (size_t)TOKENS * D_HID;      // [512][768]  bf16
    unsigned short* w2b = w1b + (size_t)D_HID * D_REAL;      // [4096][512] bf16
    // d_out doubles as scratch for gathered bf16 A — fully overwritten by GEMM2.
    unsigned short* Ag  = (unsigned short*)d_out;            // [8192][768] bf16

    const int n1 = D_HID * D_REAL / 4, n2 = D_MODEL * D_HID / 4;
    convert2_bf16<<<(n1 + n2 + 255) / 256, 256, 0, stream>>>(w1, w1b, n1, w2, w2b, n2);
    gather_bf16<<<TOKENS, 192, 0, stream>>>(real, ids, Ag);

    dim3 g1(TOKENS / 64, D_HID / 128);
    gemm1_mfma<<<g1, 256, 0, stream>>>(Ag, w1b, Hb);

    ln_elu_bf16<<<TOKENS / 4, 256, 0, stream>>>(Hb, ln_w, ln_b);

    gemm2_mfma<<<2048, 256, 0, stream>>>(Hb, w2b, ids, embed, out);
}

// Round 8
// 124.340 us; speedup vs baseline: 1.3130x; 1.3130x over previous
//
#include <hip/hip_runtime.h>
#include <hip/hip_bf16.h>
#include <math.h>

#define TOKENS 8192
#define D_REAL 768
#define D_HID  512
#define D_MODEL 4096

typedef __attribute__((ext_vector_type(8))) short bf16x8;   // 8 bf16 in 4 VGPRs
typedef __attribute__((ext_vector_type(4))) float f32x4;    // MFMA accumulator

// fp32 -> bf16, round-to-nearest-even
__device__ inline unsigned short f2bf(float f) {
    union { float f; unsigned u; } v; v.f = f;
    unsigned r = v.u + 0x7FFFu + ((v.u >> 16) & 1u);
    return (unsigned short)(r >> 16);
}
__device__ inline float bf2f(unsigned short h) {
    union { unsigned u; float f; } v; v.u = ((unsigned)h) << 16;
    return v.f;
}

// async global->LDS, 16B per lane. LDS dest = wave-uniform base + lane*16.
__device__ inline void gload_lds16(const void* g, void* lds_wave_base) {
    __builtin_amdgcn_global_load_lds(
        (const __attribute__((address_space(1))) unsigned*)g,
        (__attribute__((address_space(3))) unsigned*)lds_wave_base,
        16, 0, 0);
}

// compiler-fence + hw barrier (no implicit waitcnt drain, unlike __syncthreads)
__device__ inline void BAR() {
    asm volatile("" ::: "memory");
    __builtin_amdgcn_s_barrier();
    asm volatile("" ::: "memory");
}

// ---------------------------------------------------------------------------
// GEMM1 (round-6 form, single-buffer): Hb = Ag * w1b^T, bf16 out.
// Tile 64x128, BK=32, 4 waves (2x2). Grid (128,4) = 512 blocks.
// ---------------------------------------------------------------------------
__global__ __launch_bounds__(256)
void gemm1_mfma(const unsigned short* __restrict__ A,
                const unsigned short* __restrict__ B,
                unsigned short* __restrict__ C)
{
    constexpr int K = D_REAL, N = D_HID;
    __shared__ __align__(16) unsigned short As[64 * 32];    // 4 KB
    __shared__ __align__(16) unsigned short Bs[128 * 32];   // 8 KB

    const int tid = threadIdx.x;
    const int rowBase = blockIdx.x * 64;
    const int colBase = blockIdx.y * 128;

    const int srow = tid >> 2;
    const int scol = (tid & 3) * 8;
    const unsigned short* gA = A + (size_t)(rowBase + srow) * K + scol;
    const unsigned short* gB = B + (size_t)(colBase + srow) * K + scol;
    unsigned short* lA = As + (tid >> 6) * 512;   // wave stages 16 rows = 1 KB
    unsigned short* lB = Bs + (tid >> 6) * 512;

    const int lane = tid & 63;
    const int wv   = tid >> 6;
    const int wm   = (wv >> 1) * 32;
    const int wn   = (wv & 1) * 64;
    const int frow = lane & 15;
    const int fk   = (lane >> 4) * 8;

    f32x4 acc[2][4];
    #pragma unroll
    for (int i = 0; i < 2; i++)
        #pragma unroll
        for (int j = 0; j < 4; j++) acc[i][j] = (f32x4)0.f;

    for (int k0 = 0; k0 < K; k0 += 32) {
        gload_lds16(gA,                lA);
        gload_lds16(gB,                lB);
        gload_lds16(gB + (size_t)64*K, lB + 2048);
        gA += 32; gB += 32;
        __syncthreads();

        bf16x8 af[2], bg[4];
        #pragma unroll
        for (int i = 0; i < 2; i++)
            af[i] = *reinterpret_cast<const bf16x8*>(&As[(wm + i*16 + frow) * 32 + fk]);
        #pragma unroll
        for (int j = 0; j < 4; j++)
            bg[j] = *reinterpret_cast<const bf16x8*>(&Bs[(wn + j*16 + frow) * 32 + fk]);

        #pragma unroll
        for (int i = 0; i < 2; i++)
            #pragma unroll
            for (int j = 0; j < 4; j++)
                acc[i][j] = __builtin_amdgcn_mfma_f32_16x16x32_bf16(af[i], bg[j], acc[i][j], 0, 0, 0);
        __syncthreads();
    }

    const int orow0 = wm + (lane >> 4) * 4;
    const int ocol0 = wn + frow;
    #pragma unroll
    for (int i = 0; i < 2; i++)
        #pragma unroll
        for (int r = 0; r < 4; r++) {
            unsigned short* dst = C + (size_t)(rowBase + orow0 + i*16 + r) * N + colBase + ocol0;
            #pragma unroll
            for (int j = 0; j < 4; j++)
                dst[j * 16] = f2bf(acc[i][j][r]);
        }
}

// ---------------------------------------------------------------------------
// GEMM2, 8-phase 256x256 schedule (T3+T4+T2+T5):
//   out[8192][4096] = Hb * w2b^T + embed[ids], fp32 out.
// BM=BN=256, BK=64, 512 thr = 8 waves (2Mx4N), per-wave 128x64 = 8x4 frags.
// LDS 128 KB: A[2buf][2half][128][64] bf16 + B same. Staged via gload_lds
// with inverse-swizzled SOURCE (16B-slot XOR row&7) + swizzled ds_read.
// Per K-tile: 4 phases {ds_read subtile; stage 1 half; bar; MFMA; bar}.
// Stagger: phase p of kt stages half (p+1)&3 of kt+1 (p<3) / A-half0 of
// kt+2 (p==3, issued post-barrier after last reads of that region).
// Counted vmcnt(2) once per K-tile boundary; vmcnt(0) only at tail.
// ---------------------------------------------------------------------------
__global__ __launch_bounds__(512, 2)
void gemm2_8phase(const unsigned short* __restrict__ A,
                  const unsigned short* __restrict__ B,
                  const int* __restrict__ ids,
                  const float* __restrict__ embed,
                  float* __restrict__ C)
{
    constexpr int K = D_HID, N = D_MODEL, NKT = K / 64;   // 8 K-tiles
    __shared__ __align__(16) unsigned short lds[65536];   // 128 KiB
    __shared__ int sIds[256];
    unsigned short* Alds = lds;            // [2buf][2half][128][64]
    unsigned short* Blds = lds + 32768;

    // bijective XCD-slab swizzle over 512 blocks (32 row-tiles x 16 col-tiles)
    const int f   = blockIdx.x;
    const int xcd = f & 7;
    const int idx = f >> 3;                         // 0..63
    const int rowBase = (xcd * 4 + (idx & 3)) * 256;
    const int colBase = (idx >> 2) * 256;

    const int tid  = threadIdx.x;
    const int lane = tid & 63;
    const int wv   = tid >> 6;     // 0..7
    const int wr   = wv >> 2;      // 0..1  (M half)
    const int wc   = wv & 3;       // 0..3  (N quarter)
    const int frow = lane & 15;
    const int fq   = lane >> 4;    // 0..3

    if (tid < 256) sIds[tid] = ids[rowBase + tid];

    // stage half h (128 rows x 64 k) of K-tile kt of matrix M -> buf kt&1
    auto STAGE_HALF = [&](const unsigned short* Mp, unsigned short* Ml,
                          int tileBase, int kt, int h) {
        const int buf = kt & 1;
        #pragma unroll
        for (int u = 0; u < 2; ++u) {
            const int c    = u * 512 + tid;          // chunk 0..1023
            const int row  = c >> 3;                 // 0..127
            const int slot = (c & 7) ^ (row & 7);    // inverse swizzle on source
            const unsigned short* g = Mp + (size_t)(tileBase + h * 128 + row) * K
                                         + kt * 64 + slot * 8;
            unsigned short* l = Ml + (buf * 2 + h) * 8192 + (u * 512 + wv * 64) * 8;
            gload_lds16(g, l);
        }
    };
    auto STAGE = [&](int kt_s, int h_s) {
        if (kt_s >= NKT) return;
        if (h_s < 2) STAGE_HALF(A, Alds, rowBase, kt_s, h_s);
        else         STAGE_HALF(B, Blds, colBase, kt_s, h_s - 2);
    };
    auto LDA = [&](int buf, int mf, int kk) -> bf16x8 {
        const int row  = mf * 16 + frow;             // within half wr
        const int slot = (kk * 4 + fq) ^ (row & 7);
        return *reinterpret_cast<const bf16x8*>(
            Alds + (buf * 2 + wr) * 8192 + row * 64 + slot * 8);
    };
    auto LDB = [&](int buf, int nf, int kk) -> bf16x8 {
        const int rb   = wc * 64 + nf * 16 + frow;   // 0..255
        const int row  = rb & 127;
        const int slot = (kk * 4 + fq) ^ (row & 7);
        return *reinterpret_cast<const bf16x8*>(
            Blds + (buf * 2 + (rb >> 7)) * 8192 + row * 64 + slot * 8);
    };

    f32x4 acc[8][4];
    #pragma unroll
    for (int i = 0; i < 8; i++)
        #pragma unroll
        for (int j = 0; j < 4; j++) acc[i][j] = (f32x4)0.f;

    // prologue: all 4 halves of kt0 + A-half0 of kt1; allow kt1's A0 in flight
    STAGE(0, 0); STAGE(0, 1); STAGE(0, 2); STAGE(0, 3); STAGE(1, 0);
    asm volatile("s_waitcnt vmcnt(2)" ::: "memory");
    __builtin_amdgcn_s_barrier();
    asm volatile("" ::: "memory");

    #pragma unroll
    for (int kt = 0; kt < NKT; ++kt) {
        const int buf = kt & 1;
        bf16x8 bg[4][2];
        #pragma unroll
        for (int p = 0; p < 4; ++p) {
            bf16x8 af[2][2];
            #pragma unroll
            for (int i = 0; i < 2; ++i)
                #pragma unroll
                for (int kk = 0; kk < 2; ++kk)
                    af[i][kk] = LDA(buf, p * 2 + i, kk);
            if (p == 0) {
                #pragma unroll
                for (int nf = 0; nf < 4; ++nf)
                    #pragma unroll
                    for (int kk = 0; kk < 2; ++kk)
                        bg[nf][kk] = LDB(buf, nf, kk);
            }
            if (p < 3) STAGE(kt + 1, p + 1);   // targets buf^1: race-free
            BAR();
            if (p == 3) STAGE(kt + 2, 0);      // targets buf A-half0: issued after
                                               // its last reads crossed the barrier
            __builtin_amdgcn_s_setprio(1);
            #pragma unroll
            for (int i = 0; i < 2; ++i)
                #pragma unroll
                for (int nf = 0; nf < 4; ++nf)
                    #pragma unroll
                    for (int kk = 0; kk < 2; ++kk)
                        acc[p*2+i][nf] = __builtin_amdgcn_mfma_f32_16x16x32_bf16(
                            af[i][kk], bg[nf][kk], acc[p*2+i][nf], 0, 0, 0);
            __builtin_amdgcn_s_setprio(0);
            if (p == 3) {                      // K-tile boundary: counted drain
                if (kt + 2 < NKT)      asm volatile("s_waitcnt vmcnt(2)" ::: "memory");
                else if (kt + 1 < NKT) asm volatile("s_waitcnt vmcnt(0)" ::: "memory");
            }
            BAR();
        }
    }

    // epilogue: scalar fp32 stores + embed gather-add (C/D: row=fq*4+r, col=frow)
    const int ocol0 = colBase + wc * 64 + frow;
    #pragma unroll
    for (int mf = 0; mf < 8; ++mf) {
        #pragma unroll
        for (int r = 0; r < 4; ++r) {
            const int lrow = wr * 128 + mf * 16 + fq * 4 + r;
            const float* e = embed + (size_t)sIds[lrow] * N + ocol0;
            float* o = C + (size_t)(rowBase + lrow) * N + ocol0;
            #pragma unroll
            for (int nf = 0; nf < 4; ++nf)
                o[nf * 16] = acc[mf][nf][r] + e[nf * 16];
        }
    }
}

// ---------------------------------------------------------------------------
// fp32 -> bf16 bulk convert of w1 and w2 in one launch
// ---------------------------------------------------------------------------
__global__ __launch_bounds__(256)
void convert2_bf16(const float* __restrict__ s1, unsigned short* __restrict__ d1, int n1,
                   const float* __restrict__ s2, unsigned short* __restrict__ d2, int n2)
{
    int i = blockIdx.x * 256 + threadIdx.x;
    const float* src; unsigned short* dst;
    if (i < n1) { src = s1; dst = d1; }
    else {
        i -= n1;
        if (i >= n2) return;
        src = s2; dst = d2;
    }
    const float4 v = reinterpret_cast<const float4*>(src)[i];
    ushort4 o;
    o.x = f2bf(v.x); o.y = f2bf(v.y); o.z = f2bf(v.z); o.w = f2bf(v.w);
    reinterpret_cast<ushort4*>(dst)[i] = o;
}

// ---------------------------------------------------------------------------
// Gather rows of real[ids[t]] -> bf16 Ag[t]. One block (192 thr) per token.
// ---------------------------------------------------------------------------
__global__ __launch_bounds__(192)
void gather_bf16(const float* __restrict__ real, const int* __restrict__ ids,
                 unsigned short* __restrict__ Ag)
{
    const int row = blockIdx.x;
    const int t = threadIdx.x;
    const float4 v = *reinterpret_cast<const float4*>(real + (size_t)ids[row] * D_REAL + t * 4);
    ushort4 o;
    o.x = f2bf(v.x); o.y = f2bf(v.y); o.z = f2bf(v.z); o.w = f2bf(v.w);
    *reinterpret_cast<ushort4*>(Ag + (size_t)row * D_REAL + t * 4) = o;
}

// ---------------------------------------------------------------------------
// In-place LayerNorm + ELU on bf16 H [TOKENS][512]. One wave per row.
// ---------------------------------------------------------------------------
__global__ __launch_bounds__(256)
void ln_elu_bf16(unsigned short* __restrict__ H,
                 const float* __restrict__ ln_w, const float* __restrict__ ln_b)
{
    const int row = blockIdx.x * 4 + (threadIdx.x >> 6);
    const int t = threadIdx.x & 63;
    unsigned short* x = H + (size_t)row * D_HID + t * 8;

    bf16x8 v = *reinterpret_cast<const bf16x8*>(x);
    float fv[8], s = 0.f, ss = 0.f;
    #pragma unroll
    for (int j = 0; j < 8; j++) {
        fv[j] = bf2f((unsigned short)v[j]);
        s += fv[j]; ss += fv[j] * fv[j];
    }
    #pragma unroll
    for (int off = 32; off > 0; off >>= 1) {
        s  += __shfl_down(s, off);
        ss += __shfl_down(ss, off);
    }
    s = __shfl(s, 0); ss = __shfl(ss, 0);
    const float mu = s * (1.f / D_HID);
    const float var = ss * (1.f / D_HID) - mu * mu;
    const float rstd = rsqrtf(var + 1e-5f);

    const float4 w0 = *reinterpret_cast<const float4*>(ln_w + t * 8);
    const float4 w1 = *reinterpret_cast<const float4*>(ln_w + t * 8 + 4);
    const float4 b0 = *reinterpret_cast<const float4*>(ln_b + t * 8);
    const float4 b1 = *reinterpret_cast<const float4*>(ln_b + t * 8 + 4);
    const float wa[8] = { w0.x, w0.y, w0.z, w0.w, w1.x, w1.y, w1.z, w1.w };
    const float ba[8] = { b0.x, b0.y, b0.z, b0.w, b1.x, b1.y, b1.z, b1.w };

    bf16x8 o;
    #pragma unroll
    for (int j = 0; j < 8; j++) {
        float y = (fv[j] - mu) * rstd * wa[j] + ba[j];
        y = y > 0.f ? y : expm1f(y);
        o[j] = (short)f2bf(y);
    }
    *reinterpret_cast<bf16x8*>(x) = o;
}

extern "C" void kernel_launch(void* const* d_in, const int* in_sizes, int n_in,
                              void* d_out, int out_size, void* d_ws, size_t ws_size,
                              hipStream_t stream)
{
    const float* real  = (const float*)d_in[0];   // [32000, 768]
    const float* embed = (const float*)d_in[1];   // [32000, 4096]
    const float* w1    = (const float*)d_in[2];   // [512, 768]
    const float* w2    = (const float*)d_in[3];   // [4096, 512]
    const float* ln_w  = (const float*)d_in[4];   // [512]
    const float* ln_b  = (const float*)d_in[5];   // [512]
    const int*   ids   = (const int*)d_in[6];     // [8192]
    float* out = (float*)d_out;                   // [8192, 4096] fp32

    unsigned short* Hb  = (unsigned short*)d_ws;             // [8192][512] bf16
    unsigned short* w1b = Hb  + (size_t)TOKENS * D_HID;      // [512][768]  bf16
    unsigned short* w2b = w1b + (size_t)D_HID * D_REAL;      // [4096][512] bf16
    // d_out doubles as scratch for gathered bf16 A — fully overwritten by GEMM2.
    unsigned short* Ag  = (unsigned short*)d_out;            // [8192][768] bf16

    const int n1 = D_HID * D_REAL / 4, n2 = D_MODEL * D_HID / 4;
    convert2_bf16<<<(n1 + n2 + 255) / 256, 256, 0, stream>>>(w1, w1b, n1, w2, w2b, n2);
    gather_bf16<<<TOKENS, 192, 0, stream>>>(real, ids, Ag);

    dim3 g1(TOKENS / 64, D_HID / 128);
    gemm1_mfma<<<g1, 256, 0, stream>>>(Ag, w1b, Hb);

    ln_elu_bf16<<<TOKENS / 4, 256, 0, stream>>>(Hb, ln_w, ln_b);

    gemm2_8phase<<<512, 512, 0, stream>>>(Hb, w2b, ids, embed, out);
}